// Round 1
// baseline (220.543 us; speedup 1.0000x reference)
//
#include <hip/hip_runtime.h>
#include <hip/hip_bf16.h>

#define D_DIM 640
#define M_DIM 1024
#define B_DIM 32
#define BK 32
#define OUT_ROW 205120  // 640*641/2

typedef __bf16 bf16x8 __attribute__((ext_vector_type(8)));
typedef float f32x4 __attribute__((ext_vector_type(4)));

__device__ __forceinline__ unsigned short f2bf(float f) {
    union { float f; unsigned int u; } c; c.f = f;
    unsigned int u = c.u;
    unsigned int r = (u + 0x7fffu + ((u >> 16) & 1u)) >> 16;
    return (unsigned short)r;
}

__device__ __forceinline__ void gload_lds16(const unsigned short* g, unsigned short* l) {
    __builtin_amdgcn_global_load_lds(
        (const __attribute__((address_space(1))) unsigned int*)g,
        (__attribute__((address_space(3))) unsigned int*)l,
        16, 0, 0);
}

__device__ __forceinline__ float block_reduce_256(float s) {
    #pragma unroll
    for (int off = 32; off > 0; off >>= 1) s += __shfl_down(s, off, 64);
    __shared__ float red[4];
    if ((threadIdx.x & 63) == 0) red[threadIdx.x >> 6] = s;
    __syncthreads();
    return red[0] + red[1] + red[2] + red[3];
}

// Kernel 1: fp32 -> bf16 cast + per-row sum of squares (diag of Gram).
// One block per (b*D + i) row of 1024 elements. 20480 blocks x 256 threads.
__global__ void cast_diag_kernel(const float* __restrict__ x,
                                 unsigned short* __restrict__ xb,
                                 float* __restrict__ diag) {
    const size_t row = blockIdx.x;
    const int t = threadIdx.x;
    const float4 v = ((const float4*)(x + row * M_DIM))[t];
    float s = v.x * v.x + v.y * v.y + v.z * v.z + v.w * v.w;
    ushort4 o;
    o.x = f2bf(v.x); o.y = f2bf(v.y); o.z = f2bf(v.z); o.w = f2bf(v.w);
    ((ushort4*)(xb + row * M_DIM))[t] = o;
    float tot = block_reduce_256(s);
    if (t == 0) diag[row] = tot;
}

// Kernel 2: batched G = X X^T with fused dcov epilogue.
// Grid (5 jt, 5 it, 32 b), 256 threads (4 waves, 2x2 wave grid, 64x64 per wave).
__global__ __launch_bounds__(256, 2)
void gemm_dcov_kernel(const unsigned short* __restrict__ xb,
                      const float* __restrict__ diag,
                      float* __restrict__ dcov) {
    __shared__ __align__(16) unsigned short smem[2 * 128 * BK];
    unsigned short* sA = smem;
    unsigned short* sB = smem + 128 * BK;

    const int jt = blockIdx.x, it = blockIdx.y, bt = blockIdx.z;
    const int tid = threadIdx.x;
    const int w = tid >> 6, l = tid & 63;
    const int wy = w >> 1, wx = w & 1;
    const int lm = l & 15, quad = l >> 4;

    const unsigned short* gA = xb + ((size_t)bt * D_DIM + it * 128) * M_DIM;
    const unsigned short* gB = xb + ((size_t)bt * D_DIM + jt * 128) * M_DIM;

    // staging: thread t loads elements [t*8, t*8+8) and +2048 of each tile
    const int e0 = tid * 8;
    const int r0 = e0 >> 5;   // row within tile (BK=32 wide)
    const int c0 = e0 & 31;

    f32x4 acc[4][4];
    const f32x4 zero = {0.f, 0.f, 0.f, 0.f};
    #pragma unroll
    for (int i = 0; i < 4; i++)
        #pragma unroll
        for (int j = 0; j < 4; j++) acc[i][j] = zero;

    for (int k0 = 0; k0 < M_DIM; k0 += BK) {
        gload_lds16(gA + (size_t)r0 * M_DIM + k0 + c0,        sA + e0);
        gload_lds16(gA + (size_t)(r0 + 64) * M_DIM + k0 + c0, sA + e0 + 64 * BK);
        gload_lds16(gB + (size_t)r0 * M_DIM + k0 + c0,        sB + e0);
        gload_lds16(gB + (size_t)(r0 + 64) * M_DIM + k0 + c0, sB + e0 + 64 * BK);
        __syncthreads();

        bf16x8 af[4], bfg[4];
        #pragma unroll
        for (int mi = 0; mi < 4; mi++)
            af[mi] = *(const bf16x8*)&sA[(wy * 64 + mi * 16 + lm) * BK + quad * 8];
        #pragma unroll
        for (int ni = 0; ni < 4; ni++)
            bfg[ni] = *(const bf16x8*)&sB[(wx * 64 + ni * 16 + lm) * BK + quad * 8];

        #pragma unroll
        for (int mi = 0; mi < 4; mi++)
            #pragma unroll
            for (int ni = 0; ni < 4; ni++)
                acc[mi][ni] = __builtin_amdgcn_mfma_f32_16x16x32_bf16(
                    af[mi], bfg[ni], acc[mi][ni], 0, 0, 0);
        __syncthreads();
    }

    // stage diag slices in LDS (reuse smem)
    float* sd = (float*)smem;
    if (tid < 128) sd[tid]       = diag[(size_t)bt * D_DIM + it * 128 + tid];
    else           sd[tid]       = diag[(size_t)bt * D_DIM + jt * 128 + (tid - 128)];
    __syncthreads();

    const float temp = 7.62939453125e-07f;  // 1/(2*640*1024)
    float* dbase = dcov + (size_t)bt * D_DIM * D_DIM;
    #pragma unroll
    for (int mi = 0; mi < 4; mi++) {
        #pragma unroll
        for (int r = 0; r < 4; r++) {
            const int lrow = wy * 64 + mi * 16 + quad * 4 + r;
            const int grow = it * 128 + lrow;
            const float di = sd[lrow];
            #pragma unroll
            for (int ni = 0; ni < 4; ni++) {
                const int lcol = wx * 64 + ni * 16 + lm;
                const int gcol = jt * 128 + lcol;
                const float dj = sd[128 + lcol];
                const float g = acc[mi][ni][r];
                const float v = sqrtf(fmaf(temp, fmaxf(di + dj - 2.f * g, 0.f), 1e-5f));
                dbase[(size_t)grow * D_DIM + gcol] = v;
            }
        }
    }
}

// Kernel 3: row sums of dcov. One block per (b*D + i). 20480 blocks.
__global__ void rowsum_kernel(const float* __restrict__ dcov,
                              float* __restrict__ rowsum) {
    const size_t row = blockIdx.x;
    const float* p = dcov + row * D_DIM;
    float s = 0.f;
    for (int j = threadIdx.x; j < D_DIM; j += 256) s += p[j];
    float t = block_reduce_256(s);
    if (threadIdx.x == 0) rowsum[row] = t;
}

// Kernel 4: per-batch total = sum of rowsums. 32 blocks.
__global__ void totals_kernel(const float* __restrict__ rowsum,
                              float* __restrict__ tot) {
    const float* p = rowsum + (size_t)blockIdx.x * D_DIM;
    float s = 0.f;
    for (int j = threadIdx.x; j < D_DIM; j += 256) s += p[j];
    float t = block_reduce_256(s);
    if (threadIdx.x == 0) tot[blockIdx.x] = t;
}

// Kernel 5: double centering + triu gather. One block per (b*D + i).
__global__ void output_kernel(const float* __restrict__ dcov,
                              const float* __restrict__ rowsum,
                              const float* __restrict__ tot,
                              float* __restrict__ out) {
    const int b = blockIdx.x / D_DIM;
    const int i = blockIdx.x % D_DIM;
    const float inv_d = 1.f / (float)D_DIM;
    const float rmi = rowsum[(size_t)b * D_DIM + i] * inv_d;
    const float tm = tot[b] * (inv_d * inv_d);
    const float* drow = dcov + ((size_t)b * D_DIM + i) * D_DIM;
    const float* rs = rowsum + (size_t)b * D_DIM;
    float* orow = out + (size_t)b * OUT_ROW + (size_t)i * D_DIM - (size_t)i * (i - 1) / 2;
    for (int j = i + threadIdx.x; j < D_DIM; j += 256)
        orow[j - i] = drow[j] - rmi - rs[j] * inv_d + tm;
}

extern "C" void kernel_launch(void* const* d_in, const int* in_sizes, int n_in,
                              void* d_out, int out_size, void* d_ws, size_t ws_size,
                              hipStream_t stream) {
    const float* x = (const float*)d_in[0];
    float* out = (float*)d_out;

    char* ws = (char*)d_ws;
    unsigned short* xb = (unsigned short*)ws;              // 32*640*1024*2 = 41,943,040 B
    size_t off = 41943040;
    float* diag = (float*)(ws + off);  off += 81920;        // 32*640*4
    float* dcov = (float*)(ws + off);  off += 52428800;     // 32*640*640*4
    float* rowsum = (float*)(ws + off); off += 81920;       // 32*640*4
    float* tot = (float*)(ws + off);   off += 256;          // 32*4 (padded)

    cast_diag_kernel<<<dim3(B_DIM * D_DIM), 256, 0, stream>>>(x, xb, diag);
    gemm_dcov_kernel<<<dim3(5, 5, B_DIM), 256, 0, stream>>>(xb, diag, dcov);
    rowsum_kernel<<<dim3(B_DIM * D_DIM), 256, 0, stream>>>(dcov, rowsum);
    totals_kernel<<<dim3(B_DIM), 256, 0, stream>>>(rowsum, tot);
    output_kernel<<<dim3(B_DIM * D_DIM), 256, 0, stream>>>(dcov, rowsum, tot, out);
}

// Round 2
// 184.745 us; speedup vs baseline: 1.1938x; 1.1938x over previous
//
#include <hip/hip_runtime.h>

#define D_DIM 640
#define M_DIM 1024
#define B_DIM 32
#define BK 32
#define OUT_ROW 205120  // 640*641/2

typedef __bf16 bf16x8 __attribute__((ext_vector_type(8)));
typedef float f32x4 __attribute__((ext_vector_type(4)));

__device__ __forceinline__ unsigned short f2bf(float f) {
    union { float f; unsigned int u; } c; c.f = f;
    unsigned int u = c.u;
    unsigned int r = (u + 0x7fffu + ((u >> 16) & 1u)) >> 16;
    return (unsigned short)r;
}

__device__ __forceinline__ void gload_lds16(const unsigned short* g, unsigned short* l) {
    __builtin_amdgcn_global_load_lds(
        (const __attribute__((address_space(1))) unsigned int*)g,
        (__attribute__((address_space(3))) unsigned int*)l,
        16, 0, 0);
}

__device__ __forceinline__ float block_reduce_256(float s) {
    #pragma unroll
    for (int off = 32; off > 0; off >>= 1) s += __shfl_down(s, off, 64);
    __shared__ float red[4];
    if ((threadIdx.x & 63) == 0) red[threadIdx.x >> 6] = s;
    __syncthreads();
    return red[0] + red[1] + red[2] + red[3];
}

// Kernel 1: fp32 -> bf16 cast + per-row sum of squares; also zeroes the
// rowsum/tot accumulators consumed by the GEMM epilogue atomics.
__global__ void cast_diag_kernel(const float* __restrict__ x,
                                 unsigned short* __restrict__ xb,
                                 float* __restrict__ diag,
                                 float* __restrict__ rowsum,
                                 float* __restrict__ tot) {
    const size_t row = blockIdx.x;
    const int t = threadIdx.x;
    const float4 v = ((const float4*)(x + row * M_DIM))[t];
    float s = v.x * v.x + v.y * v.y + v.z * v.z + v.w * v.w;
    ushort4 o;
    o.x = f2bf(v.x); o.y = f2bf(v.y); o.z = f2bf(v.z); o.w = f2bf(v.w);
    ((ushort4*)(xb + row * M_DIM))[t] = o;
    float ssum = block_reduce_256(s);
    if (t == 0) { diag[row] = ssum; rowsum[row] = 0.f; }
    if (t == 1 && row < B_DIM) tot[row] = 0.f;
}

// Kernel 2: symmetric batched G = X X^T, upper-triangular tiles only
// (it<=jt), with fused dcov epilogue + rowsum/tot atomic accumulation.
// Grid (15 tile-pairs, 32 batches), 256 threads (2x2 waves, 64x64 each).
// LDS XOR swizzle: physical 16B chunk c of row r holds logical chunk
// c ^ ((r>>1)&3)  -> ds_read_b128 frag reads are uniform 2-way (free).
__global__ __launch_bounds__(256, 2)
void gemm_dcov_kernel(const unsigned short* __restrict__ xb,
                      const float* __restrict__ diag,
                      float* __restrict__ dcov,
                      float* __restrict__ rowsum,
                      float* __restrict__ tot) {
    __shared__ __align__(16) unsigned short smem[2 * 128 * BK];
    unsigned short* sA = smem;
    unsigned short* sB = smem + 128 * BK;

    // decode upper-tri tile pair: p -> (it, jt), it<=jt, 5x5 tile grid
    int p = blockIdx.x, bt = blockIdx.y;
    int it = 0, off = p;
    while (off >= 5 - it) { off -= 5 - it; ++it; }
    const int jt = it + off;
    const bool diagTile = (it == jt);

    const int tid = threadIdx.x;
    const int w = tid >> 6, l = tid & 63;
    const int wy = w >> 1, wx = w & 1;
    const int lm = l & 15, quad = l >> 4;

    const unsigned short* gA = xb + ((size_t)bt * D_DIM + it * 128) * M_DIM;
    const unsigned short* gB = xb + ((size_t)bt * D_DIM + jt * 128) * M_DIM;

    // staging: lane writes LDS at tid*16B (fixed by global_load_lds);
    // choose the global source chunk so the LDS layout is XOR-swizzled.
    const int r0 = tid >> 2;                                   // row 0..63
    const int cl = (((tid & 3) ^ ((tid >> 3) & 3)) << 3);      // logical col
    const size_t aoff1 = (size_t)r0 * M_DIM + cl;
    const size_t aoff2 = (size_t)(r0 + 64) * M_DIM + cl;
    const int ldst = tid * 8;

    f32x4 acc[4][4];
    const f32x4 zero = {0.f, 0.f, 0.f, 0.f};
    #pragma unroll
    for (int i = 0; i < 4; i++)
        #pragma unroll
        for (int j = 0; j < 4; j++) acc[i][j] = zero;

    const int sw = ((quad ^ ((lm >> 1) & 3)) << 3);  // swizzled chunk offset

    for (int k0 = 0; k0 < M_DIM; k0 += BK) {
        gload_lds16(gA + aoff1 + k0, sA + ldst);
        gload_lds16(gA + aoff2 + k0, sA + ldst + 64 * BK);
        if (!diagTile) {
            gload_lds16(gB + aoff1 + k0, sB + ldst);
            gload_lds16(gB + aoff2 + k0, sB + ldst + 64 * BK);
        }
        __syncthreads();

        const unsigned short* sBB = diagTile ? sA : sB;
        bf16x8 af[4], bfr[4];
        #pragma unroll
        for (int mi = 0; mi < 4; mi++)
            af[mi] = *(const bf16x8*)&sA[(wy * 64 + mi * 16 + lm) * BK + sw];
        #pragma unroll
        for (int ni = 0; ni < 4; ni++)
            bfr[ni] = *(const bf16x8*)&sBB[(wx * 64 + ni * 16 + lm) * BK + sw];

        #pragma unroll
        for (int mi = 0; mi < 4; mi++)
            #pragma unroll
            for (int ni = 0; ni < 4; ni++)
                acc[mi][ni] = __builtin_amdgcn_mfma_f32_16x16x32_bf16(
                    af[mi], bfr[ni], acc[mi][ni], 0, 0, 0);
        __syncthreads();
    }

    // stage diag slices in LDS (reuse smem)
    float* sd = (float*)smem;
    if (tid < 128) sd[tid] = diag[(size_t)bt * D_DIM + it * 128 + tid];
    else           sd[tid] = diag[(size_t)bt * D_DIM + jt * 128 + (tid - 128)];
    __syncthreads();

    const float temp = 7.62939453125e-07f;  // 1/(2*640*1024)
    float* dbase = dcov + (size_t)bt * D_DIM * D_DIM;
    float* rs = rowsum + (size_t)bt * D_DIM;
    float ts = 0.f;
    float cp[4] = {0.f, 0.f, 0.f, 0.f};

    #pragma unroll
    for (int mi = 0; mi < 4; mi++) {
        #pragma unroll
        for (int r = 0; r < 4; r++) {
            const int lrow = wy * 64 + mi * 16 + quad * 4 + r;
            const int grow = it * 128 + lrow;
            const float di = sd[lrow];
            float rp = 0.f;
            #pragma unroll
            for (int ni = 0; ni < 4; ni++) {
                const int lcol = wx * 64 + ni * 16 + lm;
                const int gcol = jt * 128 + lcol;
                const float dj = sd[128 + lcol];
                const float g = acc[mi][ni][r];
                const float v = sqrtf(fmaf(temp, fmaxf(di + dj - 2.f * g, 0.f), 1e-5f));
                dbase[(size_t)grow * D_DIM + gcol] = v;
                rp += v;
                cp[ni] += v;
            }
            ts += rp;
            // reduce over the 16 lanes (lm) sharing this row
            rp += __shfl_down(rp, 8, 16);
            rp += __shfl_down(rp, 4, 16);
            rp += __shfl_down(rp, 2, 16);
            rp += __shfl_down(rp, 1, 16);
            if (lm == 0) atomicAdd(&rs[grow], rp);
        }
    }
    if (!diagTile) {
        // mirrored lower tile (jt,it): its row sums == our column sums
        #pragma unroll
        for (int ni = 0; ni < 4; ni++) {
            float c = cp[ni];
            c += __shfl_down(c, 32);
            c += __shfl_down(c, 16);
            if (l < 16) atomicAdd(&rs[jt * 128 + wx * 64 + ni * 16 + lm], c);
        }
    }
    float bs = block_reduce_256(ts);
    if (tid == 0) atomicAdd(&tot[bt], diagTile ? bs : 2.f * bs);
}

// Kernel 3: double centering + triu gather. One block per (b, i) row.
__global__ void output_kernel(const float* __restrict__ dcov,
                              const float* __restrict__ rowsum,
                              const float* __restrict__ tot,
                              float* __restrict__ out) {
    const int b = blockIdx.x / D_DIM;
    const int i = blockIdx.x - b * D_DIM;
    const float inv_d = 1.f / (float)D_DIM;
    const float rmi = rowsum[(size_t)b * D_DIM + i] * inv_d;
    const float tm = tot[b] * (inv_d * inv_d);
    const float* drow = dcov + ((size_t)b * D_DIM + i) * D_DIM;
    const float* rs = rowsum + (size_t)b * D_DIM;
    float* orow = out + (size_t)b * OUT_ROW + (size_t)i * D_DIM - (size_t)i * (i - 1) / 2;
    for (int j = i + threadIdx.x; j < D_DIM; j += 256)
        orow[j - i] = drow[j] - rmi - rs[j] * inv_d + tm;
}

extern "C" void kernel_launch(void* const* d_in, const int* in_sizes, int n_in,
                              void* d_out, int out_size, void* d_ws, size_t ws_size,
                              hipStream_t stream) {
    const float* x = (const float*)d_in[0];
    float* out = (float*)d_out;

    char* ws = (char*)d_ws;
    unsigned short* xb = (unsigned short*)ws;               // 32*640*1024*2 = 41,943,040 B
    size_t off = 41943040;
    float* diag = (float*)(ws + off);   off += 81920;       // 32*640*4
    float* dcov = (float*)(ws + off);   off += 52428800;    // 32*640*640*4
    float* rowsum = (float*)(ws + off); off += 81920;       // 32*640*4
    float* tot = (float*)(ws + off);    off += 256;         // 32*4 (padded)

    cast_diag_kernel<<<dim3(B_DIM * D_DIM), 256, 0, stream>>>(x, xb, diag, rowsum, tot);
    gemm_dcov_kernel<<<dim3(15, B_DIM), 256, 0, stream>>>(xb, diag, dcov, rowsum, tot);
    output_kernel<<<dim3(B_DIM * D_DIM), 256, 0, stream>>>(dcov, rowsum, tot, out);
}

// Round 4
// 175.708 us; speedup vs baseline: 1.2552x; 1.0514x over previous
//
#include <hip/hip_runtime.h>

#define D_DIM 640
#define M_DIM 1024
#define B_DIM 32
#define BK 32
#define OUT_ROW 205120  // 640*641/2

typedef __bf16 bf16x8 __attribute__((ext_vector_type(8)));
typedef float f32x4 __attribute__((ext_vector_type(4)));

__device__ __forceinline__ unsigned short f2bf(float f) {
    union { float f; unsigned int u; } c; c.f = f;
    unsigned int u = c.u;
    unsigned int r = (u + 0x7fffu + ((u >> 16) & 1u)) >> 16;
    return (unsigned short)r;
}

__device__ __forceinline__ void gload_lds16(const unsigned short* g, unsigned short* l) {
    __builtin_amdgcn_global_load_lds(
        (const __attribute__((address_space(1))) unsigned int*)g,
        (__attribute__((address_space(3))) unsigned int*)l,
        16, 0, 0);
}

__device__ __forceinline__ float block_reduce_256(float s) {
    #pragma unroll
    for (int off = 32; off > 0; off >>= 1) s += __shfl_down(s, off, 64);
    __shared__ float red[4];
    if ((threadIdx.x & 63) == 0) red[threadIdx.x >> 6] = s;
    __syncthreads();
    return red[0] + red[1] + red[2] + red[3];
}

// Kernel 1: fp32 -> bf16 cast + per-row sum of squares; zeroes accumulators.
__global__ void cast_diag_kernel(const float* __restrict__ x,
                                 unsigned short* __restrict__ xb,
                                 float* __restrict__ diag,
                                 float* __restrict__ rowsum,
                                 float* __restrict__ tot) {
    const size_t row = blockIdx.x;
    const int t = threadIdx.x;
    const float4 v = ((const float4*)(x + row * M_DIM))[t];
    float s = v.x * v.x + v.y * v.y + v.z * v.z + v.w * v.w;
    ushort4 o;
    o.x = f2bf(v.x); o.y = f2bf(v.y); o.z = f2bf(v.z); o.w = f2bf(v.w);
    ((ushort4*)(xb + row * M_DIM))[t] = o;
    float ssum = block_reduce_256(s);
    if (t == 0) { diag[row] = ssum; rowsum[row] = 0.f; }
    if (t == 1 && row < B_DIM) tot[row] = 0.f;
}

// Kernel 2: symmetric batched G = X X^T, upper-tri tiles (it<=jt), fused
// dcov epilogue + rowsum/tot atomics.
// 3-deep software pipeline: 3 LDS phase buffers (48 KB). Barriers/waits are
// inline asm WITH "memory" clobber: R3 used IntrNoMem builtins and the
// compiler reordered ds_reads across them -> stale-phase reads (absmax 7.6e-3).
// The clobber is the compiler fence; the HW still only waits vmcnt(N).
__global__ __launch_bounds__(256, 2)
void gemm_dcov_kernel(const unsigned short* __restrict__ xb,
                      const float* __restrict__ diag,
                      float* __restrict__ dcov,
                      float* __restrict__ rowsum,
                      float* __restrict__ tot) {
    // 3 phases x (A 4096 + B 4096 shorts) = 24576 shorts = 48 KB
    __shared__ __align__(16) unsigned short smem[24576];

    const int id = blockIdx.x;
    const int bt = (id & 7) * 4 + ((id >> 3) & 3);  // batch; tiles of a batch share an XCD
    int p = id >> 5;                                 // 0..14 tile-pair index
    int it = 0, off = p;
    while (off >= 5 - it) { off -= 5 - it; ++it; }
    const int jt = it + off;
    const bool diagTile = (it == jt);

    const int tid = threadIdx.x;
    const int w = tid >> 6, l = tid & 63;
    const int wy = w >> 1, wx = w & 1;
    const int lm = l & 15, quad = l >> 4;

    const unsigned short* gA = xb + ((size_t)bt * D_DIM + it * 128) * M_DIM;
    const unsigned short* gB = xb + ((size_t)bt * D_DIM + jt * 128) * M_DIM;

    // staging: lane writes LDS at tid*16B (fixed by global_load_lds); pick the
    // global source chunk so LDS gets XOR-swizzled (bank-conflict-free reads).
    const int r0 = tid >> 2;
    const int cl = (((tid & 3) ^ ((tid >> 3) & 3)) << 3);
    const size_t aoff1 = (size_t)r0 * M_DIM + cl;
    const size_t aoff2 = aoff1 + (size_t)64 * M_DIM;
    const int ldst = tid * 8;

    auto issue = [&](int k, int ph) {
        unsigned short* sA = smem + ph * 8192;
        unsigned short* sB = sA + 4096;
        const int koff = k * BK;
        gload_lds16(gA + aoff1 + koff, sA + ldst);
        gload_lds16(gA + aoff2 + koff, sA + ldst + 2048);
        gload_lds16(gB + aoff1 + koff, sB + ldst);
        gload_lds16(gB + aoff2 + koff, sB + ldst + 2048);
    };

    f32x4 acc[4][4];
    const f32x4 zero = {0.f, 0.f, 0.f, 0.f};
    #pragma unroll
    for (int i = 0; i < 4; i++)
        #pragma unroll
        for (int j = 0; j < 4; j++) acc[i][j] = zero;

    const int sw = ((quad ^ ((lm >> 1) & 3)) << 3);  // swizzled chunk offset

    issue(0, 0); issue(1, 1); issue(2, 2);  // 12 loads in flight per wave

    int ph = 0;
    for (int k = 0; k < 32; ++k) {
        // wait only for phase k's 4 loads; keep the rest in flight.
        if (k < 30)       asm volatile("s_waitcnt vmcnt(8)" ::: "memory");
        else if (k == 30) asm volatile("s_waitcnt vmcnt(4)" ::: "memory");
        else              asm volatile("s_waitcnt vmcnt(0)" ::: "memory");
        asm volatile("s_barrier" ::: "memory");

        const unsigned short* sA = smem + ph * 8192;
        const unsigned short* sB = sA + 4096;
        bf16x8 af[4], bfr[4];
        #pragma unroll
        for (int mi = 0; mi < 4; mi++)
            af[mi] = *(const bf16x8*)&sA[(wy * 64 + mi * 16 + lm) * BK + sw];
        #pragma unroll
        for (int ni = 0; ni < 4; ni++)
            bfr[ni] = *(const bf16x8*)&sB[(wx * 64 + ni * 16 + lm) * BK + sw];

        #pragma unroll
        for (int mi = 0; mi < 4; mi++)
            #pragma unroll
            for (int ni = 0; ni < 4; ni++)
                acc[mi][ni] = __builtin_amdgcn_mfma_f32_16x16x32_bf16(
                    af[mi], bfr[ni], acc[mi][ni], 0, 0, 0);

        asm volatile("s_barrier" ::: "memory");  // all waves done reading ph
        if (k + 3 < 32) issue(k + 3, ph);
        ph = (ph == 2) ? 0 : ph + 1;
    }

    // stage diag slices in LDS (reuse smem; safe after final barrier)
    float* sd = (float*)smem;
    if (tid < 128) sd[tid] = diag[(size_t)bt * D_DIM + it * 128 + tid];
    else           sd[tid] = diag[(size_t)bt * D_DIM + jt * 128 + (tid - 128)];
    __syncthreads();

    const float temp = 7.62939453125e-07f;  // 1/(2*640*1024)
    float* dbase = dcov + (size_t)bt * D_DIM * D_DIM;
    float* rs = rowsum + (size_t)bt * D_DIM;
    float ts = 0.f;
    float cp[4] = {0.f, 0.f, 0.f, 0.f};

    #pragma unroll
    for (int mi = 0; mi < 4; mi++) {
        #pragma unroll
        for (int r = 0; r < 4; r++) {
            const int lrow = wy * 64 + mi * 16 + quad * 4 + r;
            const int grow = it * 128 + lrow;
            const float di = sd[lrow];
            float rp = 0.f;
            #pragma unroll
            for (int ni = 0; ni < 4; ni++) {
                const int lcol = wx * 64 + ni * 16 + lm;
                const int gcol = jt * 128 + lcol;
                const float dj = sd[128 + lcol];
                const float g = acc[mi][ni][r];
                const float v = sqrtf(fmaf(temp, fmaxf(di + dj - 2.f * g, 0.f), 1e-5f));
                dbase[(size_t)grow * D_DIM + gcol] = v;
                rp += v;
                cp[ni] += v;
            }
            ts += rp;
            rp += __shfl_down(rp, 8, 16);
            rp += __shfl_down(rp, 4, 16);
            rp += __shfl_down(rp, 2, 16);
            rp += __shfl_down(rp, 1, 16);
            if (lm == 0) atomicAdd(&rs[grow], rp);
        }
    }
    if (!diagTile) {
        // mirrored lower tile (jt,it): its row sums == our column sums
        #pragma unroll
        for (int ni = 0; ni < 4; ni++) {
            float c = cp[ni];
            c += __shfl_down(c, 32);
            c += __shfl_down(c, 16);
            if (l < 16) atomicAdd(&rs[jt * 128 + wx * 64 + ni * 16 + lm], c);
        }
    }
    float bs = block_reduce_256(ts);
    if (tid == 0) atomicAdd(&tot[bt], diagTile ? bs : 2.f * bs);
}

// Kernel 3: double centering + triu gather. One block per (b, i) row.
__global__ void output_kernel(const float* __restrict__ dcov,
                              const float* __restrict__ rowsum,
                              const float* __restrict__ tot,
                              float* __restrict__ out) {
    const int b = blockIdx.x / D_DIM;
    const int i = blockIdx.x - b * D_DIM;
    const float inv_d = 1.f / (float)D_DIM;
    const float rmi = rowsum[(size_t)b * D_DIM + i] * inv_d;
    const float tm = tot[b] * (inv_d * inv_d);
    const float* drow = dcov + ((size_t)b * D_DIM + i) * D_DIM;
    const float* rs = rowsum + (size_t)b * D_DIM;
    float* orow = out + (size_t)b * OUT_ROW + (size_t)i * D_DIM - (size_t)i * (i - 1) / 2;
    for (int j = i + threadIdx.x; j < D_DIM; j += 256)
        orow[j - i] = drow[j] - rmi - rs[j] * inv_d + tm;
}

extern "C" void kernel_launch(void* const* d_in, const int* in_sizes, int n_in,
                              void* d_out, int out_size, void* d_ws, size_t ws_size,
                              hipStream_t stream) {
    const float* x = (const float*)d_in[0];
    float* out = (float*)d_out;

    char* ws = (char*)d_ws;
    unsigned short* xb = (unsigned short*)ws;               // 41,943,040 B
    size_t off = 41943040;
    float* diag = (float*)(ws + off);   off += 81920;
    float* dcov = (float*)(ws + off);   off += 52428800;
    float* rowsum = (float*)(ws + off); off += 81920;
    float* tot = (float*)(ws + off);    off += 256;

    cast_diag_kernel<<<dim3(B_DIM * D_DIM), 256, 0, stream>>>(x, xb, diag, rowsum, tot);
    gemm_dcov_kernel<<<dim3(480), 256, 0, stream>>>(xb, diag, dcov, rowsum, tot);
    output_kernel<<<dim3(B_DIM * D_DIM), 256, 0, stream>>>(dcov, rowsum, tot, out);
}

// Round 5
// 171.496 us; speedup vs baseline: 1.2860x; 1.0246x over previous
//
#include <hip/hip_runtime.h>

#define D_DIM 640
#define M_DIM 1024
#define B_DIM 32
#define BK 32
#define OUT_ROW 205120  // 640*641/2

typedef __bf16 bf16x8 __attribute__((ext_vector_type(8)));
typedef float f32x4 __attribute__((ext_vector_type(4)));

__device__ __forceinline__ unsigned short f2bf(float f) {
    union { float f; unsigned int u; } c; c.f = f;
    unsigned int u = c.u;
    unsigned int r = (u + 0x7fffu + ((u >> 16) & 1u)) >> 16;
    return (unsigned short)r;
}

__device__ __forceinline__ float bf2f(unsigned short h) {
    union { unsigned int u; float f; } c; c.u = ((unsigned int)h) << 16;
    return c.f;
}

__device__ __forceinline__ void gload_lds16(const unsigned short* g, unsigned short* l) {
    __builtin_amdgcn_global_load_lds(
        (const __attribute__((address_space(1))) unsigned int*)g,
        (__attribute__((address_space(3))) unsigned int*)l,
        16, 0, 0);
}

__device__ __forceinline__ float block_reduce_256(float s) {
    #pragma unroll
    for (int off = 32; off > 0; off >>= 1) s += __shfl_down(s, off, 64);
    __shared__ float red[4];
    if ((threadIdx.x & 63) == 0) red[threadIdx.x >> 6] = s;
    __syncthreads();
    return red[0] + red[1] + red[2] + red[3];
}

// Kernel 1: fp32 -> bf16 cast + per-row sum of squares; zeroes accumulators.
__global__ void cast_diag_kernel(const float* __restrict__ x,
                                 unsigned short* __restrict__ xb,
                                 float* __restrict__ diag,
                                 float* __restrict__ rowsum,
                                 float* __restrict__ tot) {
    const size_t row = blockIdx.x;
    const int t = threadIdx.x;
    const float4 v = ((const float4*)(x + row * M_DIM))[t];
    float s = v.x * v.x + v.y * v.y + v.z * v.z + v.w * v.w;
    ushort4 o;
    o.x = f2bf(v.x); o.y = f2bf(v.y); o.z = f2bf(v.z); o.w = f2bf(v.w);
    ((ushort4*)(xb + row * M_DIM))[t] = o;
    float ssum = block_reduce_256(s);
    if (t == 0) { diag[row] = ssum; rowsum[row] = 0.f; }
    if (t == 1 && row < B_DIM) tot[row] = 0.f;
}

// Kernel 2: symmetric batched G = X X^T, upper-tri tiles (it<=jt), fused
// dcov epilogue (bf16 store) + rowsum/tot atomics.
// 4-phase software pipeline (64 KB LDS), ONE barrier per K-iter: issue(k+3)
// overwrites the buffer last read at iter k-1, which the top-of-loop barrier
// already protects (3 phases needed a second read-protect barrier).
// Barriers/waits are inline asm with "memory" clobber (compiler fence) so the
// HW only waits vmcnt(N) and loads stay in flight across barriers.
__global__ __launch_bounds__(256, 2)
void gemm_dcov_kernel(const unsigned short* __restrict__ xb,
                      const float* __restrict__ diag,
                      unsigned short* __restrict__ dcov,
                      float* __restrict__ rowsum,
                      float* __restrict__ tot) {
    // 4 phases x (A 4096 + B 4096 shorts) = 32768 shorts = 64 KB
    __shared__ __align__(16) unsigned short smem[32768];

    const int id = blockIdx.x;
    const int bt = (id & 7) * 4 + ((id >> 3) & 3);  // batch; tiles of a batch share an XCD
    int p = id >> 5;                                 // 0..14 tile-pair index
    int it = 0, off = p;
    while (off >= 5 - it) { off -= 5 - it; ++it; }
    const int jt = it + off;
    const bool diagTile = (it == jt);

    const int tid = threadIdx.x;
    const int w = tid >> 6, l = tid & 63;
    const int wy = w >> 1, wx = w & 1;
    const int lm = l & 15, quad = l >> 4;

    const unsigned short* gA = xb + ((size_t)bt * D_DIM + it * 128) * M_DIM;
    const unsigned short* gB = xb + ((size_t)bt * D_DIM + jt * 128) * M_DIM;

    // staging: lane writes LDS at tid*16B (fixed by global_load_lds); pick the
    // global source chunk so LDS gets XOR-swizzled (bank-conflict-free reads).
    const int r0 = tid >> 2;
    const int cl = (((tid & 3) ^ ((tid >> 3) & 3)) << 3);
    const size_t aoff1 = (size_t)r0 * M_DIM + cl;
    const size_t aoff2 = aoff1 + (size_t)64 * M_DIM;
    const int ldst = tid * 8;

    auto issue = [&](int k, int ph) {
        unsigned short* sA = smem + ph * 8192;
        unsigned short* sB = sA + 4096;
        const int koff = k * BK;
        gload_lds16(gA + aoff1 + koff, sA + ldst);
        gload_lds16(gA + aoff2 + koff, sA + ldst + 2048);
        gload_lds16(gB + aoff1 + koff, sB + ldst);
        gload_lds16(gB + aoff2 + koff, sB + ldst + 2048);
    };

    f32x4 acc[4][4];
    const f32x4 zero = {0.f, 0.f, 0.f, 0.f};
    #pragma unroll
    for (int i = 0; i < 4; i++)
        #pragma unroll
        for (int j = 0; j < 4; j++) acc[i][j] = zero;

    const int sw = ((quad ^ ((lm >> 1) & 3)) << 3);  // swizzled chunk offset

    issue(0, 0); issue(1, 1); issue(2, 2);  // 12 loads in flight per lane

    int ph = 0;
    for (int k = 0; k < 32; ++k) {
        // wait only for phase k's 4 loads; keep the rest in flight.
        if (k < 30)       asm volatile("s_waitcnt vmcnt(8)" ::: "memory");
        else if (k == 30) asm volatile("s_waitcnt vmcnt(4)" ::: "memory");
        else              asm volatile("s_waitcnt vmcnt(0)" ::: "memory");
        asm volatile("s_barrier" ::: "memory");
        // prefetch k+3 into phase (ph+3)&3 = buffer last read at iter k-1
        if (k + 3 < 32) issue(k + 3, (ph + 3) & 3);

        const unsigned short* sA = smem + ph * 8192;
        const unsigned short* sB = sA + 4096;
        bf16x8 af[4], bfr[4];
        #pragma unroll
        for (int mi = 0; mi < 4; mi++)
            af[mi] = *(const bf16x8*)&sA[(wy * 64 + mi * 16 + lm) * BK + sw];
        #pragma unroll
        for (int ni = 0; ni < 4; ni++)
            bfr[ni] = *(const bf16x8*)&sB[(wx * 64 + ni * 16 + lm) * BK + sw];

        #pragma unroll
        for (int mi = 0; mi < 4; mi++)
            #pragma unroll
            for (int ni = 0; ni < 4; ni++)
                acc[mi][ni] = __builtin_amdgcn_mfma_f32_16x16x32_bf16(
                    af[mi], bfr[ni], acc[mi][ni], 0, 0, 0);

        ph = (ph + 1) & 3;
    }

    // stage diag slices in LDS (phase-0 bytes; all waves just read phase 3)
    float* sd = (float*)smem;
    if (tid < 128) sd[tid] = diag[(size_t)bt * D_DIM + it * 128 + tid];
    else           sd[tid] = diag[(size_t)bt * D_DIM + jt * 128 + (tid - 128)];
    __syncthreads();

    const float temp = 7.62939453125e-07f;  // 1/(2*640*1024)
    unsigned short* dbase = dcov + (size_t)bt * D_DIM * D_DIM;
    float* rs = rowsum + (size_t)bt * D_DIM;
    float ts = 0.f;
    float cp[4] = {0.f, 0.f, 0.f, 0.f};

    #pragma unroll
    for (int mi = 0; mi < 4; mi++) {
        #pragma unroll
        for (int r = 0; r < 4; r++) {
            const int lrow = wy * 64 + mi * 16 + quad * 4 + r;
            const int grow = it * 128 + lrow;
            const float di = sd[lrow];
            float rp = 0.f;
            #pragma unroll
            for (int ni = 0; ni < 4; ni++) {
                const int lcol = wx * 64 + ni * 16 + lm;
                const int gcol = jt * 128 + lcol;
                const float dj = sd[128 + lcol];
                const float g = acc[mi][ni][r];
                const float v = sqrtf(fmaf(temp, fmaxf(di + dj - 2.f * g, 0.f), 1e-5f));
                dbase[(size_t)grow * D_DIM + gcol] = f2bf(v);
                rp += v;
                cp[ni] += v;
            }
            ts += rp;
            rp += __shfl_down(rp, 8, 16);
            rp += __shfl_down(rp, 4, 16);
            rp += __shfl_down(rp, 2, 16);
            rp += __shfl_down(rp, 1, 16);
            if (lm == 0) atomicAdd(&rs[grow], rp);
        }
    }
    if (!diagTile) {
        // mirrored lower tile (jt,it): its row sums == our column sums
        #pragma unroll
        for (int ni = 0; ni < 4; ni++) {
            float c = cp[ni];
            c += __shfl_down(c, 32);
            c += __shfl_down(c, 16);
            if (l < 16) atomicAdd(&rs[jt * 128 + wx * 64 + ni * 16 + lm], c);
        }
    }
    float bs = block_reduce_256(ts);
    if (tid == 0) atomicAdd(&tot[bt], diagTile ? bs : 2.f * bs);
}

// Kernel 3: double centering + triu gather (bf16 dcov read, fp32 out).
__global__ void output_kernel(const unsigned short* __restrict__ dcov,
                              const float* __restrict__ rowsum,
                              const float* __restrict__ tot,
                              float* __restrict__ out) {
    const int b = blockIdx.x / D_DIM;
    const int i = blockIdx.x - b * D_DIM;
    const float inv_d = 1.f / (float)D_DIM;
    const float rmi = rowsum[(size_t)b * D_DIM + i] * inv_d;
    const float tm = tot[b] * (inv_d * inv_d);
    const unsigned short* drow = dcov + ((size_t)b * D_DIM + i) * D_DIM;
    const float* rs = rowsum + (size_t)b * D_DIM;
    float* orow = out + (size_t)b * OUT_ROW + (size_t)i * D_DIM - (size_t)i * (i - 1) / 2;
    for (int j = i + threadIdx.x; j < D_DIM; j += 256)
        orow[j - i] = bf2f(drow[j]) - rmi - rs[j] * inv_d + tm;
}

extern "C" void kernel_launch(void* const* d_in, const int* in_sizes, int n_in,
                              void* d_out, int out_size, void* d_ws, size_t ws_size,
                              hipStream_t stream) {
    const float* x = (const float*)d_in[0];
    float* out = (float*)d_out;

    char* ws = (char*)d_ws;
    unsigned short* xb = (unsigned short*)ws;                 // 41,943,040 B
    size_t off = 41943040;
    float* diag = (float*)(ws + off);           off += 81920;
    unsigned short* dcov = (unsigned short*)(ws + off); off += 26214400;  // bf16
    float* rowsum = (float*)(ws + off);         off += 81920;
    float* tot = (float*)(ws + off);            off += 256;

    cast_diag_kernel<<<dim3(B_DIM * D_DIM), 256, 0, stream>>>(x, xb, diag, rowsum, tot);
    gemm_dcov_kernel<<<dim3(480), 256, 0, stream>>>(xb, diag, dcov, rowsum, tot);
    output_kernel<<<dim3(B_DIM * D_DIM), 256, 0, stream>>>(dcov, rowsum, tot, out);
}